// Round 18
// baseline (721.756 us; speedup 1.0000x reference)
//
#include <hip/hip_runtime.h>
#include <hip/hip_bf16.h>
#include <math.h>

#define D 256
#define B_ 32
#define NV 512
#define NK 2048

typedef __bf16 bf16x8 __attribute__((ext_vector_type(8)));
typedef float f32x4 __attribute__((ext_vector_type(4)));

// ---------------------------------------------------------------------------
// K0: question projections  q@W + b  for 4 (W,b,dst) triples
// ---------------------------------------------------------------------------
__global__ __launch_bounds__(256) void qproj_kernel(
    const float* __restrict__ q,
    const float* __restrict__ W0, const float* __restrict__ bias0, float* __restrict__ dst0,
    const float* __restrict__ W1, const float* __restrict__ bias1, float* __restrict__ dst1,
    const float* __restrict__ W2, const float* __restrict__ bias2, float* __restrict__ dst2,
    const float* __restrict__ W3, const float* __restrict__ bias3, float* __restrict__ dst3)
{
    int b = blockIdx.x, which = blockIdx.y, c = threadIdx.x;
    const float* W; const float* bias; float* dst;
    switch (which) {
        case 0:  W = W0; bias = bias0; dst = dst0; break;
        case 1:  W = W1; bias = bias1; dst = dst1; break;
        case 2:  W = W2; bias = bias2; dst = dst2; break;
        default: W = W3; bias = bias3; dst = dst3; break;
    }
    __shared__ float qv[D];
    qv[c] = q[b * D + c];
    __syncthreads();
    float acc = bias[c];
    #pragma unroll 8
    for (int k = 0; k < D; ++k)
        acc = fmaf(qv[k], W[k * D + c], acc);
    dst[b * D + c] = acc;
}

// ---------------------------------------------------------------------------
// wt_convert_all: Wt[col][k] (bf16) = W[k][col] (f32) for all 4 matrices.
// ---------------------------------------------------------------------------
__global__ __launch_bounds__(256) void wt_convert_all_kernel(
    const float* __restrict__ Wkv, const float* __restrict__ Wvv,
    const float* __restrict__ Wvg, const float* __restrict__ Wkg,
    __hip_bfloat16* __restrict__ wkv, __hip_bfloat16* __restrict__ wvv,
    __hip_bfloat16* __restrict__ wvg, __hip_bfloat16* __restrict__ wkg)
{
    int bx = blockIdx.x;
    const float* W; __hip_bfloat16* Wt; int K, lb;
    if (bx < 4)       { W = Wkv; Wt = wkv; K = 256; lb = bx; }
    else if (bx < 8)  { W = Wvv; Wt = wvv; K = 256; lb = bx - 4; }
    else if (bx < 16) { W = Wvg; Wt = wvg; K = 512; lb = bx - 8; }
    else              { W = Wkg; Wt = wkg; K = 512; lb = bx - 16; }
    int col = threadIdx.x;
    int k0 = lb * 64;
    for (int kk = 0; kk < 64; ++kk) {
        int k = k0 + kk;
        Wt[(size_t)col * K + k] = __float2bfloat16(W[(size_t)k * D + col]);
    }
}

// ---------------------------------------------------------------------------
// proj_ln_kernel v7 (r13/r14, proven: VGPR 40, no spill): 512 thr, 64x256
// tile, BK=32, padded 50 KB LDS. FMA chain & LN identical to r1.
// ---------------------------------------------------------------------------
__global__ __launch_bounds__(512) void proj_ln_kernel(
    const float* __restrict__ Xa, const float* __restrict__ Wa,
    const float* __restrict__ ba, const float* __restrict__ qa,
    const float* __restrict__ ga, const float* __restrict__ bea,
    const float* __restrict__ Xb, const float* __restrict__ Wb,
    const float* __restrict__ bb, const float* __restrict__ qb,
    const float* __restrict__ gb, const float* __restrict__ beb,
    float* __restrict__ outa, float* __restrict__ outb)
{
    __shared__ float xs[32][68];
    __shared__ float ws[32][260];
    __shared__ float addv[D];
    __shared__ float gam[D], bet[D];
    __shared__ float red[64][17];
    __shared__ float mrow[64], rrow[64];

    const int tid = threadIdx.x;
    const int tr = tid & 31, tc = tid >> 5;
    const int bx = blockIdx.x;

    const float* X; const float* W; float* out;
    int m0, b;
    if (bx < 256) {
        X = Xa; W = Wa; out = outa;
        m0 = bx * 64; b = m0 / NV;
        if (tid < 256) {
            addv[tid] = ba[tid] + qa[b * D + tid];
            gam[tid] = ga[tid]; bet[tid] = bea[tid];
        }
    } else {
        X = Xb; W = Wb; out = outb;
        m0 = (bx - 256) * 64; b = m0 / NK;
        if (tid < 256) {
            addv[tid] = bb[tid] + qb[b * D + tid];
            gam[tid] = gb[tid]; bet[tid] = beb[tid];
        }
    }

    float acc[2][16];
    #pragma unroll
    for (int i = 0; i < 2; ++i)
        #pragma unroll
        for (int c = 0; c < 16; ++c) acc[i][c] = 0.f;

    for (int k0 = 0; k0 < D; k0 += 32) {
        __syncthreads();
        {
            int r = tid & 63, k4 = tid >> 6;
            float4 v = *(const float4*)(X + (size_t)(m0 + r) * D + k0 + 4 * k4);
            xs[4 * k4 + 0][r] = v.x; xs[4 * k4 + 1][r] = v.y;
            xs[4 * k4 + 2][r] = v.z; xs[4 * k4 + 3][r] = v.w;
        }
        #pragma unroll
        for (int p = 0; p < 4; ++p) {
            int lin = tid + 512 * p;
            int c4 = lin & 63, kk = lin >> 6;
            *(float4*)&ws[kk][4 * c4] = *(const float4*)(W + (size_t)(k0 + kk) * D + 4 * c4);
        }
        __syncthreads();
        #pragma unroll
        for (int kk = 0; kk < 32; ++kk) {
            float2 xv = *(const float2*)&xs[kk][2 * tr];
            float xa[2] = {xv.x, xv.y};
            #pragma unroll
            for (int u = 0; u < 4; ++u) {
                float4 wv = *(const float4*)&ws[kk][16 * tc + 4 * u];
                float wa[4] = {wv.x, wv.y, wv.z, wv.w};
                #pragma unroll
                for (int i = 0; i < 2; ++i)
                    #pragma unroll
                    for (int j = 0; j < 4; ++j)
                        acc[i][4 * u + j] = fmaf(xa[i], wa[j], acc[i][4 * u + j]);
            }
        }
    }
    __syncthreads();

    #pragma unroll
    for (int i = 0; i < 2; ++i)
        #pragma unroll
        for (int c = 0; c < 16; ++c)
            acc[i][c] += addv[16 * tc + c];

    #pragma unroll
    for (int i = 0; i < 2; ++i) {
        float s = 0.f;
        #pragma unroll
        for (int c = 0; c < 16; ++c) s += acc[i][c];
        red[2 * tr + i][tc] = s;
    }
    __syncthreads();
    if (tid < 64) {
        float s = 0.f;
        #pragma unroll
        for (int t = 0; t < 16; ++t) s += red[tid][t];
        mrow[tid] = s * (1.f / 256.f);
    }
    __syncthreads();
    #pragma unroll
    for (int i = 0; i < 2; ++i) {
        float m = mrow[2 * tr + i], s = 0.f;
        #pragma unroll
        for (int c = 0; c < 16; ++c) { float d = acc[i][c] - m; s = fmaf(d, d, s); }
        red[2 * tr + i][tc] = s;
    }
    __syncthreads();
    if (tid < 64) {
        float s = 0.f;
        #pragma unroll
        for (int t = 0; t < 16; ++t) s += red[tid][t];
        float v = s * (1.f / 256.f);
        rrow[tid] = 1.0f / sqrtf(v + 1e-5f);
    }
    __syncthreads();
    #pragma unroll
    for (int i = 0; i < 2; ++i) {
        float m = mrow[2 * tr + i], rs = rrow[2 * tr + i];
        size_t rbase = (size_t)(m0 + 2 * tr + i) * D;
        #pragma unroll
        for (int u = 0; u < 4; ++u) {
            float o[4];
            #pragma unroll
            for (int j = 0; j < 4; ++j) {
                int c = 16 * tc + 4 * u + j;
                o[j] = (acc[i][4 * u + j] - m) * rs * gam[c] + bet[c];
            }
            *(float4*)(out + rbase + 16 * tc + 4 * u) = make_float4(o[0], o[1], o[2], o[3]);
        }
    }
}

// ---------------------------------------------------------------------------
// top-4 helpers: stable (ties -> lower index), sorted descending.
// ---------------------------------------------------------------------------
__device__ __forceinline__ void top4_insert(float (&s)[4], int (&id)[4], float cs, int ci)
{
    if (cs > s[3] || (cs == s[3] && ci < id[3])) {
        s[3] = cs; id[3] = ci;
        #pragma unroll
        for (int k = 3; k > 0; --k) {
            bool sw = (s[k] > s[k-1]) || (s[k] == s[k-1] && id[k] < id[k-1]);
            if (sw) {
                float tf = s[k]; s[k] = s[k-1]; s[k-1] = tf;
                int   ti_ = id[k]; id[k] = id[k-1]; id[k-1] = ti_;
            }
        }
    }
}

__device__ __forceinline__ bool better_pair(float sa, int ia, float sb, int ib)
{
    return (sa > sb) || (sa == sb && ia < ib);
}

__device__ __forceinline__ void ce_pair(float& s0, int& i0, float& s1, int& i1)
{
    bool sw = !better_pair(s0, i0, s1, i1);
    float as = sw ? s1 : s0, bs = sw ? s0 : s1;
    int   ai = sw ? i1 : i0, bi = sw ? i0 : i1;
    s0 = as; i0 = ai; s1 = bs; i1 = bi;
}

__device__ __forceinline__ void bitonic_merge_stage(float (&s)[4], int (&id)[4], int mask)
{
    float os[4]; int oi[4];
    #pragma unroll
    for (int e = 0; e < 4; ++e) {
        os[e] = __shfl_xor(s[e], mask);
        oi[e] = __shfl_xor(id[e], mask);
    }
    #pragma unroll
    for (int e = 0; e < 4; ++e) {
        float bs2 = os[3 - e]; int bi2 = oi[3 - e];
        bool k = better_pair(s[e], id[e], bs2, bi2);
        s[e] = k ? s[e] : bs2;
        id[e] = k ? id[e] : bi2;
    }
    ce_pair(s[0], id[0], s[2], id[2]);
    ce_pair(s[1], id[1], s[3], id[3]);
    ce_pair(s[0], id[0], s[1], id[1]);
    ce_pair(s[2], id[2], s[3], id[3]);
}

// ---------------------------------------------------------------------------
// score_gemm_kernel v5: 512 threads, 256x128 tile, 8x8 patch (acc=64 VGPR).
// r17 was LDS-read bound (3 b128 / 32 FMA); 8x8 gives 4 b128 / 64 FMA (1.5x).
// LDS padded to 53.5 KB (A stride 724) -> exactly 2 blocks/CU by LDS ->
// allocator VGPR budget 128 >= ~100 live (the r9-proven steering mechanism;
// avoids the r10/r13 VGPR-64 cliff). FMA chain per output element: k
// ascending 0..255, single accumulator, *0.0625 at end -> bit-identical
// scores. Epilogue partials (order-independent selection):
//  - row dir: per row top4 over this block's 128 cols -> v_part[row][ct]
//    (nent 64, layout unchanged)
//  - col dir: per col top4 over 32-row groups -> k_part[col][rt*8+wave]
//    (nent 64: 2 rt x 8 waves x 4 entries)
// ---------------------------------------------------------------------------
__global__ __launch_bounds__(512) void score_gemm_kernel(
    const float* __restrict__ Qm, const float* __restrict__ Cm,
    float2* __restrict__ k_part, float2* __restrict__ v_part)
{
    __shared__ float as[16][724];   // A: [kk][row 0..255], padded stride (LDS steer)
    __shared__ float bs[16][132];   // B: [kk][col 0..127]

    const int tid = threadIdx.x;
    const int ty = tid >> 4, tx = tid & 15;   // ty 0..31 (8 rows), tx 0..15 (8 cols)
    const int half = blockIdx.x >> 9;
    const int bx = blockIdx.x & 511;
    const int xcd = bx & 7, seq = bx >> 3;    // seq 0..63
    const int bl = xcd * 2 + (seq >> 5);      // 2 batches per xcd per half
    const int tile = seq & 31;
    const int rt = tile >> 4, ct = tile & 15; // rt 0..1 (256-row), ct 0..15 (128-col)
    const int b = half * 16 + bl;

    const float* Qb = Qm + ((size_t)b * NV + rt * 256) * D;
    const float* Cb = Cm + ((size_t)b * NK + ct * 128) * D;

    float acc[8][8];
    #pragma unroll
    for (int i = 0; i < 8; ++i)
        #pragma unroll
        for (int j = 0; j < 8; ++j) acc[i][j] = 0.f;

    // prefetch regs: A 2x float4 (rows lin&255, k-group lin>>8), B 1x float4
    float4 qa[2], cb;
    #pragma unroll
    for (int p = 0; p < 2; ++p) {
        int lin = tid + 512 * p;
        int r = lin & 255, k4 = lin >> 8;
        qa[p] = *(const float4*)(Qb + (size_t)r * D + 4 * k4);
    }
    {
        int c = tid & 127, k4 = tid >> 7;
        cb = *(const float4*)(Cb + (size_t)c * D + 4 * k4);
    }

    for (int t = 0; t < 16; ++t) {
        __syncthreads();
        #pragma unroll
        for (int p = 0; p < 2; ++p) {
            int lin = tid + 512 * p;
            int r = lin & 255, k4 = lin >> 8;
            as[4*k4+0][r] = qa[p].x; as[4*k4+1][r] = qa[p].y;
            as[4*k4+2][r] = qa[p].z; as[4*k4+3][r] = qa[p].w;
        }
        {
            int c = tid & 127, k4 = tid >> 7;
            bs[4*k4+0][c] = cb.x; bs[4*k4+1][c] = cb.y;
            bs[4*k4+2][c] = cb.z; bs[4*k4+3][c] = cb.w;
        }
        __syncthreads();
        if (t < 15) {                 // issue next chunk loads; hide under FMA
            const int k0 = (t + 1) * 16;
            #pragma unroll
            for (int p = 0; p < 2; ++p) {
                int lin = tid + 512 * p;
                int r = lin & 255, k4 = lin >> 8;
                qa[p] = *(const float4*)(Qb + (size_t)r * D + k0 + 4 * k4);
            }
            {
                int c = tid & 127, k4 = tid >> 7;
                cb = *(const float4*)(Cb + (size_t)c * D + k0 + 4 * k4);
            }
        }
        #pragma unroll
        for (int kk = 0; kk < 16; ++kk) {
            float4 a0 = *(const float4*)&as[kk][8 * ty];
            float4 a1 = *(const float4*)&as[kk][8 * ty + 4];
            float4 b0 = *(const float4*)&bs[kk][4 * tx];
            float4 b1 = *(const float4*)&bs[kk][64 + 4 * tx];
            float aa[8] = {a0.x, a0.y, a0.z, a0.w, a1.x, a1.y, a1.z, a1.w};
            float bb[8] = {b0.x, b0.y, b0.z, b0.w, b1.x, b1.y, b1.z, b1.w};
            #pragma unroll
            for (int i = 0; i < 8; ++i)
                #pragma unroll
                for (int j = 0; j < 8; ++j)
                    acc[i][j] = fmaf(aa[i], bb[j], acc[i][j]);
        }
    }

    // local col ids: j<4 -> 4*tx+j ; j>=4 -> 64+4*tx+(j-4)
    // ---- row-direction partials --------------------------------------------
    #pragma unroll
    for (int i = 0; i < 8; ++i) {
        float ts[4] = {-INFINITY, -INFINITY, -INFINITY, -INFINITY};
        int   ti[4] = {0x7FFFFFFF, 0x7FFFFFFF, 0x7FFFFFFF, 0x7FFFFFFF};
        #pragma unroll
        for (int j = 0; j < 8; ++j) {
            int lc = (j < 4) ? (4 * tx + j) : (64 + 4 * tx + (j - 4));
            top4_insert(ts, ti, acc[i][j] * 0.0625f, ct * 128 + lc);
        }
        bitonic_merge_stage(ts, ti, 1);
        bitonic_merge_stage(ts, ti, 2);
        bitonic_merge_stage(ts, ti, 4);
        bitonic_merge_stage(ts, ti, 8);
        if (tx == 0) {
            size_t row_g = (size_t)b * NV + rt * 256 + 8 * ty + i;
            size_t base = (row_g * 16 + ct) * 4;
            #pragma unroll
            for (int e = 0; e < 4; ++e)
                v_part[base + e] = make_float2(ts[e], __int_as_float(ti[e]));
        }
    }
    // ---- col-direction partials --------------------------------------------
    const int rbase = rt * 256 + 8 * ty;       // row id within batch [0,512)
    #pragma unroll
    for (int j = 0; j < 8; ++j) {
        float cs2[4] = {-INFINITY, -INFINITY, -INFINITY, -INFINITY};
        int   ci2[4] = {0x7FFFFFFF, 0x7FFFFFFF, 0x7FFFFFFF, 0x7FFFFFFF};
        #pragma unroll
        for (int i = 0; i < 8; ++i)
            top4_insert(cs2, ci2, acc[i][j] * 0.0625f, rbase + i);
        bitonic_merge_stage(cs2, ci2, 16);     // merge ty^1 within wave
        bitonic_merge_stage(cs2, ci2, 32);     // merge ty^2 within wave
        if ((ty & 3) == 0) {
            int lc = (j < 4) ? (4 * tx + j) : (64 + 4 * tx + (j - 4));
            size_t col_g = (size_t)b * NK + ct * 128 + lc;
            size_t base = (col_g * 16 + rt * 8 + (ty >> 2)) * 4;
            #pragma unroll
            for (int e = 0; e < 4; ++e)
                k_part[base + e] = make_float2(cs2[e], __int_as_float(ci2[e]));
        }
    }
}

// ---------------------------------------------------------------------------
// merge_topk_all_kernel: both directions in one launch, nent=64 each.
// blocks [0,64): v rows; [64,320): k rows.
// ---------------------------------------------------------------------------
__global__ __launch_bounds__(256) void merge_topk_all_kernel(
    const float2* __restrict__ v_part, float* __restrict__ v_w, int* __restrict__ v_idx,
    const float2* __restrict__ k_part, float* __restrict__ k_w, int* __restrict__ k_idx)
{
    int bx = blockIdx.x;
    const float2* part; float* out_w; int* out_idx; int row;
    if (bx < 64) {
        part = v_part; out_w = v_w; out_idx = v_idx;
        row = bx * 256 + threadIdx.x;
    } else {
        part = k_part; out_w = k_w; out_idx = k_idx;
        row = (bx - 64) * 256 + threadIdx.x;
    }
    const float2* p = part + (size_t)row * 64;
    float bs[4] = {-INFINITY, -INFINITY, -INFINITY, -INFINITY};
    int bi[4] = {0x7FFFFFFF, 0x7FFFFFFF, 0x7FFFFFFF, 0x7FFFFFFF};
    for (int e = 0; e < 64; e += 2) {
        float4 v = *(const float4*)(p + e);
        top4_insert(bs, bi, v.x, __float_as_int(v.y));
        top4_insert(bs, bi, v.z, __float_as_int(v.w));
    }
    float m = bs[0];
    float e0 = expf(bs[0] - m), e1 = expf(bs[1] - m);
    float e2 = expf(bs[2] - m), e3 = expf(bs[3] - m);
    float inv = 1.f / (e0 + e1 + e2 + e3);
    size_t base = (size_t)row * 4;
    out_w[base + 0] = e0 * inv; out_w[base + 1] = e1 * inv;
    out_w[base + 2] = e2 * inv; out_w[base + 3] = e3 * inv;
    out_idx[base + 0] = bi[0]; out_idx[base + 1] = bi[1];
    out_idx[base + 2] = bi[2]; out_idx[base + 3] = bi[3];
}

// ---------------------------------------------------------------------------
// combine_all_kernel: both directions in one launch.
// ---------------------------------------------------------------------------
__global__ __launch_bounds__(256) void combine_all_kernel(
    const float* __restrict__ kg, const float* __restrict__ v_w, const int* __restrict__ v_idx,
    float* __restrict__ vq,
    const float* __restrict__ visual, const float* __restrict__ k_w, const int* __restrict__ k_idx,
    float* __restrict__ kq)
{
    int bx = blockIdx.x;
    const float* src; const float* wts; const int* idx; float* comb;
    int rowsPerBatch, srcRowsPerBatch, shift;
    if (bx < 4096) {
        src = kg; wts = v_w; idx = v_idx; comb = vq;
        rowsPerBatch = NV; srcRowsPerBatch = NK; shift = 7;
    } else {
        bx -= 4096;
        src = visual; wts = k_w; idx = k_idx; comb = kq;
        rowsPerBatch = NK; srcRowsPerBatch = NV; shift = 9;
    }
    int xcd = bx & 7, seq = bx >> 3;
    int b = xcd + 8 * (seq >> shift);
    int innerB = seq & ((1 << shift) - 1);
    int row = b * rowsPerBatch + innerB * 4 + (threadIdx.x >> 6);
    int lane = threadIdx.x & 63;
    const float* sb = src + (size_t)b * srcRowsPerBatch * D;
    float4 a = make_float4(0.f, 0.f, 0.f, 0.f);
    #pragma unroll
    for (int j = 0; j < 4; ++j) {
        float w = wts[(size_t)row * 4 + j];
        int id = idx[(size_t)row * 4 + j];
        float4 v = *(const float4*)(sb + (size_t)id * D + 4 * lane);
        a.x = fmaf(w, v.x, a.x); a.y = fmaf(w, v.y, a.y);
        a.z = fmaf(w, v.z, a.z); a.w = fmaf(w, v.w, a.w);
    }
    *(float4*)(comb + (size_t)row * D + 4 * lane) = a;
}

// ---------------------------------------------------------------------------
// mfma_fused_kernel: MFMA bf16 GEMM (f32 in/out), 64 rows x 256 cols / block.
// Two param sets in one launch: blocks [0,256) = set A (NV), rest = set B (NK).
//   mode 0: out = gemm + addv            (addv = bias, unbatched)
//   mode 1: out = nodes + sigmoid(gemm + addv[b]) * msgs   (in-place safe)
// ---------------------------------------------------------------------------
__global__ __launch_bounds__(256) void mfma_fused_kernel(
    const float* XA0, const float* XA1, const __hip_bfloat16* WtA,
    const float* addvA, const float* nodesA, const float* msgsA, float* outA,
    const float* XB0, const float* XB1, const __hip_bfloat16* WtB,
    const float* addvB, const float* nodesB, const float* msgsB, float* outB,
    int nkt, int mode)
{
    __shared__ __align__(16) __hip_bfloat16 AsB[64 * 40 + 256 * 40];
    __shared__ float addv[D];
    __hip_bfloat16* As = AsB;
    __hip_bfloat16* Bs = AsB + 64 * 40;
    float* ot = (float*)AsB;                 // epilogue alias (16x264 f32)

    const int tid = threadIdx.x;
    const int lane = tid & 63, w = tid >> 6;
    const int lr = lane & 15, lg = lane >> 4;
    const int bxr = blockIdx.x;
    const bool isB = bxr >= 256;
    const float* X0 = isB ? XB0 : XA0;
    const float* X1 = isB ? XB1 : XA1;
    const __hip_bfloat16* Wt = isB ? WtB : WtA;
    const float* addv_g = isB ? addvB : addvA;
    const float* nodes = isB ? nodesB : nodesA;
    const float* msgs = isB ? msgsB : msgsA;
    float* outp = isB ? outB : outA;
    const int rowsPerBatch = isB ? NK : NV;
    const int rows0 = (isB ? bxr - 256 : bxr) * 64;
    const int K = nkt * 32;

    {
        int b = rows0 / rowsPerBatch;
        addv[tid] = addv_g[(mode ? (size_t)b * D : 0) + tid];
    }

    f32x4 acc[4][4];
    #pragma unroll
    for (int i = 0; i < 4; ++i)
        #pragma unroll
        for (int j = 0; j < 4; ++j)
            acc[i][j] = (f32x4){0.f, 0.f, 0.f, 0.f};

    const int arow = tid >> 2, akq = (tid & 3) * 8;

    for (int kt = 0; kt < nkt; ++kt) {
        {
            const float* Xc = (kt < 8) ? X0 : X1;
            int k0 = (kt & 7) * 32;
            const float* src = Xc + (size_t)(rows0 + arow) * D + k0 + akq;
            float4 a = *(const float4*)src;
            float4 bq = *(const float4*)(src + 4);
            __hip_bfloat16 tmp[8];
            tmp[0] = __float2bfloat16(a.x);  tmp[1] = __float2bfloat16(a.y);
            tmp[2] = __float2bfloat16(a.z);  tmp[3] = __float2bfloat16(a.w);
            tmp[4] = __float2bfloat16(bq.x); tmp[5] = __float2bfloat16(bq.y);
            tmp[6] = __float2bfloat16(bq.z); tmp[7] = __float2bfloat16(bq.w);
            *(uint4*)(As + arow * 40 + akq) = *(const uint4*)tmp;
        }
        {
            const uint4* src = (const uint4*)(Wt + (size_t)tid * K + kt * 32);
            uint4* dst = (uint4*)(Bs + tid * 40);
            dst[0] = src[0]; dst[1] = src[1]; dst[2] = src[2]; dst[3] = src[3];
        }
        __syncthreads();

        bf16x8 av[4], bv[4];
        #pragma unroll
        for (int rt = 0; rt < 4; ++rt)
            av[rt] = *reinterpret_cast<const bf16x8*>(As + (rt * 16 + lr) * 40 + lg * 8);
        #pragma unroll
        for (int ct = 0; ct < 4; ++ct)
            bv[ct] = *reinterpret_cast<const bf16x8*>(Bs + (w * 64 + ct * 16 + lr) * 40 + lg * 8);
        #pragma unroll
        for (int rt = 0; rt < 4; ++rt)
            #pragma unroll
            for (int ct = 0; ct < 4; ++ct)
                acc[rt][ct] = __builtin_amdgcn_mfma_f32_16x16x32_bf16(av[rt], bv[ct], acc[rt][ct], 0, 0, 0);
        __syncthreads();
    }

    for (int rt = 0; rt < 4; ++rt) {
        #pragma unroll
        for (int ct = 0; ct < 4; ++ct)
            #pragma unroll
            for (int j = 0; j < 4; ++j)
                ot[(4 * lg + j) * 264 + w * 64 + ct * 16 + lr] = acc[rt][ct][j];
        __syncthreads();
        {
            const int lrow = tid >> 4, c0 = (tid & 15) * 16;
            const size_t gbase = (size_t)(rows0 + rt * 16 + lrow) * D + c0;
            #pragma unroll
            for (int u = 0; u < 4; ++u) {
                float4 v = *(const float4*)&ot[lrow * 264 + c0 + 4 * u];
                float4 o;
                if (mode == 0) {
                    o.x = v.x + addv[c0 + 4*u + 0];
                    o.y = v.y + addv[c0 + 4*u + 1];
                    o.z = v.z + addv[c0 + 4*u + 2];
                    o.w = v.w + addv[c0 + 4*u + 3];
                } else {
                    float4 nv = *(const float4*)(nodes + gbase + 4 * u);
                    float4 mv = *(const float4*)(msgs + gbase + 4 * u);
                    float g0 = 1.f / (1.f + expf(-(v.x + addv[c0 + 4*u + 0])));
                    float g1 = 1.f / (1.f + expf(-(v.y + addv[c0 + 4*u + 1])));
                    float g2 = 1.f / (1.f + expf(-(v.z + addv[c0 + 4*u + 2])));
                    float g3 = 1.f / (1.f + expf(-(v.w + addv[c0 + 4*u + 3])));
                    o.x = nv.x + g0 * mv.x; o.y = nv.y + g1 * mv.y;
                    o.z = nv.z + g2 * mv.z; o.w = nv.w + g3 * mv.w;
                }
                *(float4*)(outp + gbase + 4 * u) = o;
            }
        }
        __syncthreads();
    }
}

// ---------------------------------------------------------------------------
extern "C" void kernel_launch(void* const* d_in, const int* in_sizes, int n_in,
                              void* d_out, int out_size, void* d_ws, size_t ws_size,
                              hipStream_t stream)
{
    const float* visual = (const float*)d_in[0];
    const float* kg     = (const float*)d_in[1];
    const float* quest  = (const float*)d_in[2];
    const float* W_vs = (const float*)d_in[5];  const float* b_vs = (const float*)d_in[6];
    const float* W_ks = (const float*)d_in[7];  const float* b_ks = (const float*)d_in[8];
    const float* W_qv = (const float*)d_in[9];  const float* b_qv = (const float*)d_in[10];
    const float* W_qk = (const float*)d_in[11]; const float* b_qk = (const float*)d_in[12];
    const float* W_kv = (const float*)d_in[13]; const float* b_kv = (const float*)d_in[14];
    const float* W_vv = (const float*)d_in[15]; const float* b_vv = (const float*)d_in[16];
    const float* W_vg = (const float*)d_in[17]; const float* b_vg = (const float*)d_in[18];
    const float* W_kg = (const float*)d_in[19]; const float* b_kg = (const float*)d_in[20];
    const float* g_v  = (const float*)d_in[21]; const float* be_v = (const float*)d_in[22];
    const float* g_k  = (const float*)d_in[23]; const float* be_k = (const float*)d_in[24];

    float* f = (float*)d_ws;
    float* vq    = f;                    // [B*NV, D], later reused as comb_v
    float* kq    = f + 4194304;          // [B*NK, D], later reused as comb_k
    float* q_vis = f + 20971520;
    float* q_kg  = f + 20979712;
    float* qg_v  = f + 20987904;
    float* qg_k  = f + 20996096;
    float* v_w   = f + 21004288;         // [B*NV, 4]
    float* k_w   = f + 21069824;         // [B*NK, 4]
    int*   v_idx = (int*)(f + 21331968);
    int*   k_idx = (int*)(f + 21397504);
    __hip_bfloat16* wt_kv = (__hip_bfloat16*)(f + 21659648);   // 256x256
    __hip_bfloat16* wt_vv = (__hip_bfloat16*)(f + 21692416);   // 256x256
    __hip_bfloat16* wt_vg = (__hip_bfloat16*)(f + 21725184);   // 256x512
    __hip_bfloat16* wt_kg = (__hip_bfloat16*)(f + 21790720);   // 256x512
    // total ws use: 21,856,256 floats = 87.4 MB

    float* outp   = (float*)d_out;
    float* v_msgs = outp;                        // [B*NV, D] staged in d_out
    float* k_msgs = outp + (size_t)B_ * NV * D;  // [B*NK, D]
    // top-4 partials staged in d_out (free until K5):
    //   k_part: [B*NK][64] float2 = 16,777,216 floats
    //   v_part: [B*NV][64] float2 =  4,194,304 floats
    // total 20,971,520 floats = exactly d_out, NON-overlapping.
    float2* k_part = (float2*)d_out;
    float2* v_part = (float2*)((float*)d_out + 16777216);

    // one-time weight transpose+convert (all four in one launch)
    wt_convert_all_kernel<<<24, 256, 0, stream>>>(
        W_kv, W_vv, W_vg, W_kg, wt_kv, wt_vv, wt_vg, wt_kg);

    // K0: question projections (incl. gate question-term with gate bias folded)
    qproj_kernel<<<dim3(B_, 4), 256, 0, stream>>>(quest,
        W_qv, b_qv, q_vis,
        W_qk, b_qk, q_kg,
        W_vg + (size_t)512 * D, b_vg, qg_v,
        W_kg + (size_t)512 * D, b_kg, qg_k);

    // K1: projected + LayerNormed queries (f32, selection-critical), one launch
    proj_ln_kernel<<<1280, 512, 0, stream>>>(
        visual, W_vs, b_vs, q_vis, g_v, be_v,
        kg,     W_ks, b_ks, q_kg,  g_k, be_k,
        vq, kq);

    // K2: score GEMM + fused top-4 partials, both halves (1024 blocks)
    score_gemm_kernel<<<1024, 512, 0, stream>>>(vq, kq, k_part, v_part);

    // K3: merge partials -> weights + indices, both directions in one launch
    merge_topk_all_kernel<<<320, 256, 0, stream>>>(
        v_part, v_w, v_idx, k_part, k_w, k_idx);

    // K4: weighted combine of raw node rows (softmax weights sum to 1)
    combine_all_kernel<<<20480, 256, 0, stream>>>(
        kg, v_w, v_idx, vq, visual, k_w, k_idx, kq);

    // K5: message value projections (MFMA bf16), staged into d_out
    mfma_fused_kernel<<<1280, 256, 0, stream>>>(
        vq, nullptr, wt_kv, b_kv, nullptr, nullptr, v_msgs,
        kq, nullptr, wt_vv, b_vv, nullptr, nullptr, k_msgs,
        8, 0);

    // K6: gate + residual (MFMA bf16, K=512), in-place over staged messages
    mfma_fused_kernel<<<1280, 256, 0, stream>>>(
        visual, v_msgs, wt_vg, qg_v, visual, v_msgs, v_msgs,
        kg, k_msgs, wt_kg, qg_k, kg, k_msgs, k_msgs,
        16, 1);
}

// Round 19
// 662.482 us; speedup vs baseline: 1.0895x; 1.0895x over previous
//
#include <hip/hip_runtime.h>
#include <hip/hip_bf16.h>
#include <math.h>

#define D 256
#define B_ 32
#define NV 512
#define NK 2048

typedef __bf16 bf16x8 __attribute__((ext_vector_type(8)));
typedef float f32x4 __attribute__((ext_vector_type(4)));

// ---------------------------------------------------------------------------
// K0: question projections  q@W + b  for 4 (W,b,dst) triples
// ---------------------------------------------------------------------------
__global__ __launch_bounds__(256) void qproj_kernel(
    const float* __restrict__ q,
    const float* __restrict__ W0, const float* __restrict__ bias0, float* __restrict__ dst0,
    const float* __restrict__ W1, const float* __restrict__ bias1, float* __restrict__ dst1,
    const float* __restrict__ W2, const float* __restrict__ bias2, float* __restrict__ dst2,
    const float* __restrict__ W3, const float* __restrict__ bias3, float* __restrict__ dst3)
{
    int b = blockIdx.x, which = blockIdx.y, c = threadIdx.x;
    const float* W; const float* bias; float* dst;
    switch (which) {
        case 0:  W = W0; bias = bias0; dst = dst0; break;
        case 1:  W = W1; bias = bias1; dst = dst1; break;
        case 2:  W = W2; bias = bias2; dst = dst2; break;
        default: W = W3; bias = bias3; dst = dst3; break;
    }
    __shared__ float qv[D];
    qv[c] = q[b * D + c];
    __syncthreads();
    float acc = bias[c];
    #pragma unroll 8
    for (int k = 0; k < D; ++k)
        acc = fmaf(qv[k], W[k * D + c], acc);
    dst[b * D + c] = acc;
}

// ---------------------------------------------------------------------------
// wt_convert_all: Wt[col][k] (bf16) = W[k][col] (f32) for all 4 matrices.
// ---------------------------------------------------------------------------
__global__ __launch_bounds__(256) void wt_convert_all_kernel(
    const float* __restrict__ Wkv, const float* __restrict__ Wvv,
    const float* __restrict__ Wvg, const float* __restrict__ Wkg,
    __hip_bfloat16* __restrict__ wkv, __hip_bfloat16* __restrict__ wvv,
    __hip_bfloat16* __restrict__ wvg, __hip_bfloat16* __restrict__ wkg)
{
    int bx = blockIdx.x;
    const float* W; __hip_bfloat16* Wt; int K, lb;
    if (bx < 4)       { W = Wkv; Wt = wkv; K = 256; lb = bx; }
    else if (bx < 8)  { W = Wvv; Wt = wvv; K = 256; lb = bx - 4; }
    else if (bx < 16) { W = Wvg; Wt = wvg; K = 512; lb = bx - 8; }
    else              { W = Wkg; Wt = wkg; K = 512; lb = bx - 16; }
    int col = threadIdx.x;
    int k0 = lb * 64;
    for (int kk = 0; kk < 64; ++kk) {
        int k = k0 + kk;
        Wt[(size_t)col * K + k] = __float2bfloat16(W[(size_t)k * D + col]);
    }
}

// ---------------------------------------------------------------------------
// proj_ln_kernel v7 (r13/r14, proven: VGPR 40, no spill): 512 thr, 64x256
// tile, BK=32, padded 50 KB LDS. FMA chain & LN identical to r1.
// ---------------------------------------------------------------------------
__global__ __launch_bounds__(512) void proj_ln_kernel(
    const float* __restrict__ Xa, const float* __restrict__ Wa,
    const float* __restrict__ ba, const float* __restrict__ qa,
    const float* __restrict__ ga, const float* __restrict__ bea,
    const float* __restrict__ Xb, const float* __restrict__ Wb,
    const float* __restrict__ bb, const float* __restrict__ qb,
    const float* __restrict__ gb, const float* __restrict__ beb,
    float* __restrict__ outa, float* __restrict__ outb)
{
    __shared__ float xs[32][68];
    __shared__ float ws[32][260];
    __shared__ float addv[D];
    __shared__ float gam[D], bet[D];
    __shared__ float red[64][17];
    __shared__ float mrow[64], rrow[64];

    const int tid = threadIdx.x;
    const int tr = tid & 31, tc = tid >> 5;
    const int bx = blockIdx.x;

    const float* X; const float* W; float* out;
    int m0, b;
    if (bx < 256) {
        X = Xa; W = Wa; out = outa;
        m0 = bx * 64; b = m0 / NV;
        if (tid < 256) {
            addv[tid] = ba[tid] + qa[b * D + tid];
            gam[tid] = ga[tid]; bet[tid] = bea[tid];
        }
    } else {
        X = Xb; W = Wb; out = outb;
        m0 = (bx - 256) * 64; b = m0 / NK;
        if (tid < 256) {
            addv[tid] = bb[tid] + qb[b * D + tid];
            gam[tid] = gb[tid]; bet[tid] = beb[tid];
        }
    }

    float acc[2][16];
    #pragma unroll
    for (int i = 0; i < 2; ++i)
        #pragma unroll
        for (int c = 0; c < 16; ++c) acc[i][c] = 0.f;

    for (int k0 = 0; k0 < D; k0 += 32) {
        __syncthreads();
        {
            int r = tid & 63, k4 = tid >> 6;
            float4 v = *(const float4*)(X + (size_t)(m0 + r) * D + k0 + 4 * k4);
            xs[4 * k4 + 0][r] = v.x; xs[4 * k4 + 1][r] = v.y;
            xs[4 * k4 + 2][r] = v.z; xs[4 * k4 + 3][r] = v.w;
        }
        #pragma unroll
        for (int p = 0; p < 4; ++p) {
            int lin = tid + 512 * p;
            int c4 = lin & 63, kk = lin >> 6;
            *(float4*)&ws[kk][4 * c4] = *(const float4*)(W + (size_t)(k0 + kk) * D + 4 * c4);
        }
        __syncthreads();
        #pragma unroll
        for (int kk = 0; kk < 32; ++kk) {
            float2 xv = *(const float2*)&xs[kk][2 * tr];
            float xa[2] = {xv.x, xv.y};
            #pragma unroll
            for (int u = 0; u < 4; ++u) {
                float4 wv = *(const float4*)&ws[kk][16 * tc + 4 * u];
                float wa[4] = {wv.x, wv.y, wv.z, wv.w};
                #pragma unroll
                for (int i = 0; i < 2; ++i)
                    #pragma unroll
                    for (int j = 0; j < 4; ++j)
                        acc[i][4 * u + j] = fmaf(xa[i], wa[j], acc[i][4 * u + j]);
            }
        }
    }
    __syncthreads();

    #pragma unroll
    for (int i = 0; i < 2; ++i)
        #pragma unroll
        for (int c = 0; c < 16; ++c)
            acc[i][c] += addv[16 * tc + c];

    #pragma unroll
    for (int i = 0; i < 2; ++i) {
        float s = 0.f;
        #pragma unroll
        for (int c = 0; c < 16; ++c) s += acc[i][c];
        red[2 * tr + i][tc] = s;
    }
    __syncthreads();
    if (tid < 64) {
        float s = 0.f;
        #pragma unroll
        for (int t = 0; t < 16; ++t) s += red[tid][t];
        mrow[tid] = s * (1.f / 256.f);
    }
    __syncthreads();
    #pragma unroll
    for (int i = 0; i < 2; ++i) {
        float m = mrow[2 * tr + i], s = 0.f;
        #pragma unroll
        for (int c = 0; c < 16; ++c) { float d = acc[i][c] - m; s = fmaf(d, d, s); }
        red[2 * tr + i][tc] = s;
    }
    __syncthreads();
    if (tid < 64) {
        float s = 0.f;
        #pragma unroll
        for (int t = 0; t < 16; ++t) s += red[tid][t];
        float v = s * (1.f / 256.f);
        rrow[tid] = 1.0f / sqrtf(v + 1e-5f);
    }
    __syncthreads();
    #pragma unroll
    for (int i = 0; i < 2; ++i) {
        float m = mrow[2 * tr + i], rs = rrow[2 * tr + i];
        size_t rbase = (size_t)(m0 + 2 * tr + i) * D;
        #pragma unroll
        for (int u = 0; u < 4; ++u) {
            float o[4];
            #pragma unroll
            for (int j = 0; j < 4; ++j) {
                int c = 16 * tc + 4 * u + j;
                o[j] = (acc[i][4 * u + j] - m) * rs * gam[c] + bet[c];
            }
            *(float4*)(out + rbase + 16 * tc + 4 * u) = make_float4(o[0], o[1], o[2], o[3]);
        }
    }
}

// ---------------------------------------------------------------------------
// top-4 helpers: stable (ties -> lower index), sorted descending.
// ---------------------------------------------------------------------------
__device__ __forceinline__ void top4_insert(float (&s)[4], int (&id)[4], float cs, int ci)
{
    if (cs > s[3] || (cs == s[3] && ci < id[3])) {
        s[3] = cs; id[3] = ci;
        #pragma unroll
        for (int k = 3; k > 0; --k) {
            bool sw = (s[k] > s[k-1]) || (s[k] == s[k-1] && id[k] < id[k-1]);
            if (sw) {
                float tf = s[k]; s[k] = s[k-1]; s[k-1] = tf;
                int   ti_ = id[k]; id[k] = id[k-1]; id[k-1] = ti_;
            }
        }
    }
}

__device__ __forceinline__ bool better_pair(float sa, int ia, float sb, int ib)
{
    return (sa > sb) || (sa == sb && ia < ib);
}

__device__ __forceinline__ void ce_pair(float& s0, int& i0, float& s1, int& i1)
{
    bool sw = !better_pair(s0, i0, s1, i1);
    float as = sw ? s1 : s0, bs = sw ? s0 : s1;
    int   ai = sw ? i1 : i0, bi = sw ? i0 : i1;
    s0 = as; i0 = ai; s1 = bs; i1 = bi;
}

__device__ __forceinline__ void bitonic_merge_stage(float (&s)[4], int (&id)[4], int mask)
{
    float os[4]; int oi[4];
    #pragma unroll
    for (int e = 0; e < 4; ++e) {
        os[e] = __shfl_xor(s[e], mask);
        oi[e] = __shfl_xor(id[e], mask);
    }
    #pragma unroll
    for (int e = 0; e < 4; ++e) {
        float bs2 = os[3 - e]; int bi2 = oi[3 - e];
        bool k = better_pair(s[e], id[e], bs2, bi2);
        s[e] = k ? s[e] : bs2;
        id[e] = k ? id[e] : bi2;
    }
    ce_pair(s[0], id[0], s[2], id[2]);
    ce_pair(s[1], id[1], s[3], id[3]);
    ce_pair(s[0], id[0], s[1], id[1]);
    ce_pair(s[2], id[2], s[3], id[3]);
}

// ---------------------------------------------------------------------------
// score_gemm_kernel v4c (r17, proven 665us total): BOTH halves in one
// 2048-block launch (half=bx>>10, per-half decode on bx&1023). 512 threads,
// 128x128 tile, 4x8 patch. GEMM core FMA chain bit-identical. Epilogue
// emits top-4 partials for both directions (order-independent selection).
// r18's 8x8/256x128 variant regressed (occupancy 43->23%, latency-bound);
// this shape is the empirically-best operating point.
// ---------------------------------------------------------------------------
__global__ __launch_bounds__(512) void score_gemm_kernel(
    const float* __restrict__ Qm, const float* __restrict__ Cm,
    float2* __restrict__ k_part, float2* __restrict__ v_part)
{
    __shared__ float as[16][132];
    __shared__ float bs[16][132];

    const int tid = threadIdx.x;
    const int ty = tid >> 4, tx = tid & 15;
    const int half = blockIdx.x >> 10;
    const int bx = blockIdx.x & 1023;
    const int xcd = bx & 7, seq = bx >> 3;
    const int bl = xcd * 2 + (seq >> 6);
    const int tile = seq & 63;
    const int rt = tile >> 4, ct = tile & 15;
    const int b = half * 16 + bl;

    const float* Qb = Qm + ((size_t)b * NV + rt * 128) * D;
    const float* Cb = Cm + ((size_t)b * NK + ct * 128) * D;

    const int r_st = tid >> 2;
    const int g_st = tid & 3;

    float acc[4][8];
    #pragma unroll
    for (int i = 0; i < 4; ++i)
        #pragma unroll
        for (int j = 0; j < 8; ++j) acc[i][j] = 0.f;

    float4 q0 = *(const float4*)(Qb + (size_t)r_st * D + 4 * g_st);
    float4 c0 = *(const float4*)(Cb + (size_t)r_st * D + 4 * g_st);

    for (int t = 0; t < 16; ++t) {
        __syncthreads();
        as[4*g_st+0][r_st] = q0.x; as[4*g_st+1][r_st] = q0.y;
        as[4*g_st+2][r_st] = q0.z; as[4*g_st+3][r_st] = q0.w;
        bs[4*g_st+0][r_st] = c0.x; bs[4*g_st+1][r_st] = c0.y;
        bs[4*g_st+2][r_st] = c0.z; bs[4*g_st+3][r_st] = c0.w;
        __syncthreads();
        if (t < 15) {
            const int k0 = (t + 1) * 16;
            q0 = *(const float4*)(Qb + (size_t)r_st * D + k0 + 4 * g_st);
            c0 = *(const float4*)(Cb + (size_t)r_st * D + k0 + 4 * g_st);
        }
        #pragma unroll
        for (int kk = 0; kk < 16; ++kk) {
            float4 a0 = *(const float4*)&as[kk][4 * ty];
            float4 b0 = *(const float4*)&bs[kk][4 * tx];
            float4 b1 = *(const float4*)&bs[kk][64 + 4 * tx];
            float aa[4] = {a0.x, a0.y, a0.z, a0.w};
            float bb[8] = {b0.x, b0.y, b0.z, b0.w, b1.x, b1.y, b1.z, b1.w};
            #pragma unroll
            for (int i = 0; i < 4; ++i)
                #pragma unroll
                for (int j = 0; j < 8; ++j)
                    acc[i][j] = fmaf(aa[i], bb[j], acc[i][j]);
        }
    }

    // ---- row-direction partials --------------------------------------------
    #pragma unroll
    for (int i = 0; i < 4; ++i) {
        float ts[4] = {-INFINITY, -INFINITY, -INFINITY, -INFINITY};
        int   ti[4] = {0x7FFFFFFF, 0x7FFFFFFF, 0x7FFFFFFF, 0x7FFFFFFF};
        #pragma unroll
        for (int j = 0; j < 8; ++j) {
            int lc = (j < 4) ? (4 * tx + j) : (64 + 4 * tx + (j - 4));
            top4_insert(ts, ti, acc[i][j] * 0.0625f, ct * 128 + lc);
        }
        bitonic_merge_stage(ts, ti, 1);
        bitonic_merge_stage(ts, ti, 2);
        bitonic_merge_stage(ts, ti, 4);
        bitonic_merge_stage(ts, ti, 8);
        if (tx == 0) {
            size_t row_g = (size_t)b * NV + rt * 128 + 4 * ty + i;
            size_t base = (row_g * 16 + ct) * 4;
            #pragma unroll
            for (int e = 0; e < 4; ++e)
                v_part[base + e] = make_float2(ts[e], __int_as_float(ti[e]));
        }
    }
    // ---- col-direction partials --------------------------------------------
    const int rbase = rt * 128 + 4 * ty;
    #pragma unroll
    for (int j = 0; j < 8; ++j) {
        float cs2[4] = {-INFINITY, -INFINITY, -INFINITY, -INFINITY};
        int   ci2[4] = {0x7FFFFFFF, 0x7FFFFFFF, 0x7FFFFFFF, 0x7FFFFFFF};
        #pragma unroll
        for (int i = 0; i < 4; ++i)
            top4_insert(cs2, ci2, acc[i][j] * 0.0625f, rbase + i);
        bitonic_merge_stage(cs2, ci2, 16);
        bitonic_merge_stage(cs2, ci2, 32);
        if ((ty & 3) == 0) {
            int lc = (j < 4) ? (4 * tx + j) : (64 + 4 * tx + (j - 4));
            size_t col_g = (size_t)b * NK + ct * 128 + lc;
            size_t base = (col_g * 32 + rt * 8 + (ty >> 2)) * 4;
            #pragma unroll
            for (int e = 0; e < 4; ++e)
                k_part[base + e] = make_float2(cs2[e], __int_as_float(ci2[e]));
        }
    }
}

// ---------------------------------------------------------------------------
// merge_topk_all_kernel: both directions in one launch.
// blocks [0,64): v rows (nent 64); [64,320): k rows (nent 128).
// ---------------------------------------------------------------------------
__global__ __launch_bounds__(256) void merge_topk_all_kernel(
    const float2* __restrict__ v_part, float* __restrict__ v_w, int* __restrict__ v_idx,
    const float2* __restrict__ k_part, float* __restrict__ k_w, int* __restrict__ k_idx)
{
    int bx = blockIdx.x;
    const float2* part; float* out_w; int* out_idx; int row, nent;
    if (bx < 64) {
        part = v_part; out_w = v_w; out_idx = v_idx;
        row = bx * 256 + threadIdx.x; nent = 64;
    } else {
        part = k_part; out_w = k_w; out_idx = k_idx;
        row = (bx - 64) * 256 + threadIdx.x; nent = 128;
    }
    const float2* p = part + (size_t)row * nent;
    float bs[4] = {-INFINITY, -INFINITY, -INFINITY, -INFINITY};
    int bi[4] = {0x7FFFFFFF, 0x7FFFFFFF, 0x7FFFFFFF, 0x7FFFFFFF};
    for (int e = 0; e < nent; e += 2) {
        float4 v = *(const float4*)(p + e);
        top4_insert(bs, bi, v.x, __float_as_int(v.y));
        top4_insert(bs, bi, v.z, __float_as_int(v.w));
    }
    float m = bs[0];
    float e0 = expf(bs[0] - m), e1 = expf(bs[1] - m);
    float e2 = expf(bs[2] - m), e3 = expf(bs[3] - m);
    float inv = 1.f / (e0 + e1 + e2 + e3);
    size_t base = (size_t)row * 4;
    out_w[base + 0] = e0 * inv; out_w[base + 1] = e1 * inv;
    out_w[base + 2] = e2 * inv; out_w[base + 3] = e3 * inv;
    out_idx[base + 0] = bi[0]; out_idx[base + 1] = bi[1];
    out_idx[base + 2] = bi[2]; out_idx[base + 3] = bi[3];
}

// ---------------------------------------------------------------------------
// combine_all_kernel: both directions in one launch.
// ---------------------------------------------------------------------------
__global__ __launch_bounds__(256) void combine_all_kernel(
    const float* __restrict__ kg, const float* __restrict__ v_w, const int* __restrict__ v_idx,
    float* __restrict__ vq,
    const float* __restrict__ visual, const float* __restrict__ k_w, const int* __restrict__ k_idx,
    float* __restrict__ kq)
{
    int bx = blockIdx.x;
    const float* src; const float* wts; const int* idx; float* comb;
    int rowsPerBatch, srcRowsPerBatch, shift;
    if (bx < 4096) {
        src = kg; wts = v_w; idx = v_idx; comb = vq;
        rowsPerBatch = NV; srcRowsPerBatch = NK; shift = 7;
    } else {
        bx -= 4096;
        src = visual; wts = k_w; idx = k_idx; comb = kq;
        rowsPerBatch = NK; srcRowsPerBatch = NV; shift = 9;
    }
    int xcd = bx & 7, seq = bx >> 3;
    int b = xcd + 8 * (seq >> shift);
    int innerB = seq & ((1 << shift) - 1);
    int row = b * rowsPerBatch + innerB * 4 + (threadIdx.x >> 6);
    int lane = threadIdx.x & 63;
    const float* sb = src + (size_t)b * srcRowsPerBatch * D;
    float4 a = make_float4(0.f, 0.f, 0.f, 0.f);
    #pragma unroll
    for (int j = 0; j < 4; ++j) {
        float w = wts[(size_t)row * 4 + j];
        int id = idx[(size_t)row * 4 + j];
        float4 v = *(const float4*)(sb + (size_t)id * D + 4 * lane);
        a.x = fmaf(w, v.x, a.x); a.y = fmaf(w, v.y, a.y);
        a.z = fmaf(w, v.z, a.z); a.w = fmaf(w, v.w, a.w);
    }
    *(float4*)(comb + (size_t)row * D + 4 * lane) = a;
}

// ---------------------------------------------------------------------------
// mfma_fused_kernel: MFMA bf16 GEMM (f32 in/out), 64 rows x 256 cols / block.
// Two param sets in one launch: blocks [0,256) = set A (NV), rest = set B (NK).
//   mode 0: out = gemm + addv            (addv = bias, unbatched)
//   mode 1: out = nodes + sigmoid(gemm + addv[b]) * msgs   (in-place safe)
// ---------------------------------------------------------------------------
__global__ __launch_bounds__(256) void mfma_fused_kernel(
    const float* XA0, const float* XA1, const __hip_bfloat16* WtA,
    const float* addvA, const float* nodesA, const float* msgsA, float* outA,
    const float* XB0, const float* XB1, const __hip_bfloat16* WtB,
    const float* addvB, const float* nodesB, const float* msgsB, float* outB,
    int nkt, int mode)
{
    __shared__ __align__(16) __hip_bfloat16 AsB[64 * 40 + 256 * 40];
    __shared__ float addv[D];
    __hip_bfloat16* As = AsB;
    __hip_bfloat16* Bs = AsB + 64 * 40;
    float* ot = (float*)AsB;                 // epilogue alias (16x264 f32)

    const int tid = threadIdx.x;
    const int lane = tid & 63, w = tid >> 6;
    const int lr = lane & 15, lg = lane >> 4;
    const int bxr = blockIdx.x;
    const bool isB = bxr >= 256;
    const float* X0 = isB ? XB0 : XA0;
    const float* X1 = isB ? XB1 : XA1;
    const __hip_bfloat16* Wt = isB ? WtB : WtA;
    const float* addv_g = isB ? addvB : addvA;
    const float* nodes = isB ? nodesB : nodesA;
    const float* msgs = isB ? msgsB : msgsA;
    float* outp = isB ? outB : outA;
    const int rowsPerBatch = isB ? NK : NV;
    const int rows0 = (isB ? bxr - 256 : bxr) * 64;
    const int K = nkt * 32;

    {
        int b = rows0 / rowsPerBatch;
        addv[tid] = addv_g[(mode ? (size_t)b * D : 0) + tid];
    }

    f32x4 acc[4][4];
    #pragma unroll
    for (int i = 0; i < 4; ++i)
        #pragma unroll
        for (int j = 0; j < 4; ++j)
            acc[i][j] = (f32x4){0.f, 0.f, 0.f, 0.f};

    const int arow = tid >> 2, akq = (tid & 3) * 8;

    for (int kt = 0; kt < nkt; ++kt) {
        {
            const float* Xc = (kt < 8) ? X0 : X1;
            int k0 = (kt & 7) * 32;
            const float* src = Xc + (size_t)(rows0 + arow) * D + k0 + akq;
            float4 a = *(const float4*)src;
            float4 bq = *(const float4*)(src + 4);
            __hip_bfloat16 tmp[8];
            tmp[0] = __float2bfloat16(a.x);  tmp[1] = __float2bfloat16(a.y);
            tmp[2] = __float2bfloat16(a.z);  tmp[3] = __float2bfloat16(a.w);
            tmp[4] = __float2bfloat16(bq.x); tmp[5] = __float2bfloat16(bq.y);
            tmp[6] = __float2bfloat16(bq.z); tmp[7] = __float2bfloat16(bq.w);
            *(uint4*)(As + arow * 40 + akq) = *(const uint4*)tmp;
        }
        {
            const uint4* src = (const uint4*)(Wt + (size_t)tid * K + kt * 32);
            uint4* dst = (uint4*)(Bs + tid * 40);
            dst[0] = src[0]; dst[1] = src[1]; dst[2] = src[2]; dst[3] = src[3];
        }
        __syncthreads();

        bf16x8 av[4], bv[4];
        #pragma unroll
        for (int rt = 0; rt < 4; ++rt)
            av[rt] = *reinterpret_cast<const bf16x8*>(As + (rt * 16 + lr) * 40 + lg * 8);
        #pragma unroll
        for (int ct = 0; ct < 4; ++ct)
            bv[ct] = *reinterpret_cast<const bf16x8*>(Bs + (w * 64 + ct * 16 + lr) * 40 + lg * 8);
        #pragma unroll
        for (int rt = 0; rt < 4; ++rt)
            #pragma unroll
            for (int ct = 0; ct < 4; ++ct)
                acc[rt][ct] = __builtin_amdgcn_mfma_f32_16x16x32_bf16(av[rt], bv[ct], acc[rt][ct], 0, 0, 0);
        __syncthreads();
    }

    for (int rt = 0; rt < 4; ++rt) {
        #pragma unroll
        for (int ct = 0; ct < 4; ++ct)
            #pragma unroll
            for (int j = 0; j < 4; ++j)
                ot[(4 * lg + j) * 264 + w * 64 + ct * 16 + lr] = acc[rt][ct][j];
        __syncthreads();
        {
            const int lrow = tid >> 4, c0 = (tid & 15) * 16;
            const size_t gbase = (size_t)(rows0 + rt * 16 + lrow) * D + c0;
            #pragma unroll
            for (int u = 0; u < 4; ++u) {
                float4 v = *(const float4*)&ot[lrow * 264 + c0 + 4 * u];
                float4 o;
                if (mode == 0) {
                    o.x = v.x + addv[c0 + 4*u + 0];
                    o.y = v.y + addv[c0 + 4*u + 1];
                    o.z = v.z + addv[c0 + 4*u + 2];
                    o.w = v.w + addv[c0 + 4*u + 3];
                } else {
                    float4 nv = *(const float4*)(nodes + gbase + 4 * u);
                    float4 mv = *(const float4*)(msgs + gbase + 4 * u);
                    float g0 = 1.f / (1.f + expf(-(v.x + addv[c0 + 4*u + 0])));
                    float g1 = 1.f / (1.f + expf(-(v.y + addv[c0 + 4*u + 1])));
                    float g2 = 1.f / (1.f + expf(-(v.z + addv[c0 + 4*u + 2])));
                    float g3 = 1.f / (1.f + expf(-(v.w + addv[c0 + 4*u + 3])));
                    o.x = nv.x + g0 * mv.x; o.y = nv.y + g1 * mv.y;
                    o.z = nv.z + g2 * mv.z; o.w = nv.w + g3 * mv.w;
                }
                *(float4*)(outp + gbase + 4 * u) = o;
            }
        }
        __syncthreads();
    }
}

// ---------------------------------------------------------------------------
extern "C" void kernel_launch(void* const* d_in, const int* in_sizes, int n_in,
                              void* d_out, int out_size, void* d_ws, size_t ws_size,
                              hipStream_t stream)
{
    const float* visual = (const float*)d_in[0];
    const float* kg     = (const float*)d_in[1];
    const float* quest  = (const float*)d_in[2];
    const float* W_vs = (const float*)d_in[5];  const float* b_vs = (const float*)d_in[6];
    const float* W_ks = (const float*)d_in[7];  const float* b_ks = (const float*)d_in[8];
    const float* W_qv = (const float*)d_in[9];  const float* b_qv = (const float*)d_in[10];
    const float* W_qk = (const float*)d_in[11]; const float* b_qk = (const float*)d_in[12];
    const float* W_kv = (const float*)d_in[13]; const float* b_kv = (const float*)d_in[14];
    const float* W_vv = (const float*)d_in[15]; const float* b_vv = (const float*)d_in[16];
    const float* W_vg = (const float*)d_in[17]; const float* b_vg = (const float*)d_in[18];
    const float* W_kg = (const float*)d_in[19]; const float* b_kg = (const float*)d_in[20];
    const float* g_v  = (const float*)d_in[21]; const float* be_v = (const float*)d_in[22];
    const float* g_k  = (const float*)d_in[23]; const float* be_k = (const float*)d_in[24];

    float* f = (float*)d_ws;
    float* vq    = f;                    // [B*NV, D], later reused as comb_v
    float* kq    = f + 4194304;          // [B*NK, D], later reused as comb_k
    float* q_vis = f + 20971520;
    float* q_kg  = f + 20979712;
    float* qg_v  = f + 20987904;
    float* qg_k  = f + 20996096;
    float* v_w   = f + 21004288;         // [B*NV, 4]
    float* k_w   = f + 21069824;         // [B*NK, 4]
    int*   v_idx = (int*)(f + 21331968);
    int*   k_idx = (int*)(f + 21397504);
    __hip_bfloat16* wt_kv = (__hip_bfloat16*)(f + 21659648);   // 256x256
    __hip_bfloat16* wt_vv = (__hip_bfloat16*)(f + 21692416);   // 256x256
    __hip_bfloat16* wt_vg = (__hip_bfloat16*)(f + 21725184);   // 256x512
    __hip_bfloat16* wt_kg = (__hip_bfloat16*)(f + 21790720);   // 256x512
    // total ws use: 21,856,256 floats = 87.4 MB

    float* outp   = (float*)d_out;
    float* v_msgs = outp;                        // [B*NV, D] staged in d_out
    float* k_msgs = outp + (size_t)B_ * NV * D;  // [B*NK, D]
    // top-4 partials staged in d_out (free until K5):
    //   k_part: [B*NK][128] float2 = 16,777,216 floats (67.1 MB)
    //   v_part: [B*NV][64]  float2 =  2,097,152 floats ( 8.4 MB)
    float2* k_part = (float2*)d_out;
    float2* v_part = (float2*)((float*)d_out + 16777216);

    // one-time weight transpose+convert (all four in one launch)
    wt_convert_all_kernel<<<24, 256, 0, stream>>>(
        W_kv, W_vv, W_vg, W_kg, wt_kv, wt_vv, wt_vg, wt_kg);

    // K0: question projections (incl. gate question-term with gate bias folded)
    qproj_kernel<<<dim3(B_, 4), 256, 0, stream>>>(quest,
        W_qv, b_qv, q_vis,
        W_qk, b_qk, q_kg,
        W_vg + (size_t)512 * D, b_vg, qg_v,
        W_kg + (size_t)512 * D, b_kg, qg_k);

    // K1: projected + LayerNormed queries (f32, selection-critical), one launch
    proj_ln_kernel<<<1280, 512, 0, stream>>>(
        visual, W_vs, b_vs, q_vis, g_v, be_v,
        kg,     W_ks, b_ks, q_kg,  g_k, be_k,
        vq, kq);

    // K2: score GEMM + fused top-4 partials, BOTH halves in one launch
    score_gemm_kernel<<<2048, 512, 0, stream>>>(vq, kq, k_part, v_part);

    // K3: merge partials -> weights + indices, both directions in one launch
    merge_topk_all_kernel<<<320, 256, 0, stream>>>(
        v_part, v_w, v_idx, k_part, k_w, k_idx);

    // K4: weighted combine of raw node rows (softmax weights sum to 1)
    combine_all_kernel<<<20480, 256, 0, stream>>>(
        kg, v_w, v_idx, vq, visual, k_w, k_idx, kq);

    // K5: message value projections (MFMA bf16), staged into d_out
    mfma_fused_kernel<<<1280, 256, 0, stream>>>(
        vq, nullptr, wt_kv, b_kv, nullptr, nullptr, v_msgs,
        kq, nullptr, wt_vv, b_vv, nullptr, nullptr, k_msgs,
        8, 0);

    // K6: gate + residual (MFMA bf16, K=512), in-place over staged messages
    mfma_fused_kernel<<<1280, 256, 0, stream>>>(
        visual, v_msgs, wt_vg, qg_v, visual, v_msgs, v_msgs,
        kg, k_msgs, wt_kg, qg_k, kg, k_msgs, k_msgs,
        16, 1);
}